// Round 1
// baseline (363.821 us; speedup 1.0000x reference)
//
#include <hip/hip_runtime.h>
#include <hip/hip_bf16.h>
#include <stdint.h>

#define N_TOK 8192
#define D_K   1024
#define BM    128
#define BN    128
#define BK    64

typedef __attribute__((ext_vector_type(8))) short bf16x8;
typedef __attribute__((ext_vector_type(4))) float f32x4;

__global__ void zero_out_kernel(float* out) { out[0] = 0.0f; }

__device__ __forceinline__ unsigned short f32_to_bf16_rne(float x) {
  uint32_t u = __builtin_bit_cast(uint32_t, x);
  uint32_t r = (u >> 16) & 1u;
  u += 0x7fffu + r;
  return (unsigned short)(u >> 16);
}

__global__ void __launch_bounds__(256)
convert_kernel(const float* __restrict__ a, const float* __restrict__ b,
               ushort* __restrict__ oa, ushort* __restrict__ ob) {
  const size_t total4 = (size_t)N_TOK * D_K / 4;
  size_t i = (size_t)blockIdx.x * blockDim.x + threadIdx.x;
  size_t stride = (size_t)gridDim.x * blockDim.x;
  for (; i < total4; i += stride) {
    float4 va = ((const float4*)a)[i];
    float4 vb = ((const float4*)b)[i];
    ushort4 ua, ub;
    ua.x = f32_to_bf16_rne(va.x); ua.y = f32_to_bf16_rne(va.y);
    ua.z = f32_to_bf16_rne(va.z); ua.w = f32_to_bf16_rne(va.w);
    ub.x = f32_to_bf16_rne(vb.x); ub.y = f32_to_bf16_rne(vb.y);
    ub.z = f32_to_bf16_rne(vb.z); ub.w = f32_to_bf16_rne(vb.w);
    ((ushort4*)oa)[i] = ua;
    ((ushort4*)ob)[i] = ub;
  }
}

// Fused GEMM + sigmoid-contrastive loss.
// A, B: bf16 [8192][1024] row-major (both consume K => "B^T" NT GEMM).
// Each block: 128x128 logit tile; 4 waves in 2x2, each wave 64x64 via
// 4x4 fragments of mfma_f32_16x16x32_bf16.
__global__ void __launch_bounds__(256)
sigc_kernel(const ushort* __restrict__ A, const ushort* __restrict__ B,
            const int* __restrict__ labA, const int* __restrict__ labB,
            const float* __restrict__ scale_p, const float* __restrict__ bias_p,
            float* __restrict__ out) {
  __shared__ ushort sA[BM * BK];
  __shared__ ushort sB[BN * BK];
  __shared__ int sLabA[BM];
  __shared__ int sLabB[BN];
  __shared__ float sPart[4];

  const int tid  = threadIdx.x;
  const int lane = tid & 63;
  const int wid  = tid >> 6;
  const int wr   = wid >> 1;   // wave row (0/1)
  const int wc   = wid & 1;    // wave col (0/1)

  const int bRow = blockIdx.y * BM;
  const int bCol = blockIdx.x * BN;

  if (tid < BM) sLabA[tid] = labA[bRow + tid];
  else          sLabB[tid - BM] = labB[bCol + (tid - BM)];

  f32x4 acc[4][4];
#pragma unroll
  for (int i = 0; i < 4; ++i)
#pragma unroll
    for (int j = 0; j < 4; ++j) acc[i][j] = (f32x4){0.f, 0.f, 0.f, 0.f};

  // staging: tile is [128 rows][64 cols] bf16, linear in LDS.
  // 16 wave-issues of 64 lanes x 16B; wave w handles issues w*4 .. w*4+3.
  const int eBase = wid * 2048 + lane * 8;  // element index, + it*512

  for (int k0 = 0; k0 < D_K; k0 += BK) {
#pragma unroll
    for (int it = 0; it < 4; ++it) {
      const int e   = eBase + it * 512;
      const int row = e >> 6;      // /64
      const int col = e & 63;
      const int ldsOff = (wid * 4 + it) * 512;  // wave-uniform base (elements)
      const ushort* gA = A + (size_t)(bRow + row) * D_K + (k0 + col);
      const ushort* gB = B + (size_t)(bCol + row) * D_K + (k0 + col);
      __builtin_amdgcn_global_load_lds(
          (const __attribute__((address_space(1))) void*)gA,
          (__attribute__((address_space(3))) void*)(sA + ldsOff), 16, 0, 0);
      __builtin_amdgcn_global_load_lds(
          (const __attribute__((address_space(1))) void*)gB,
          (__attribute__((address_space(3))) void*)(sB + ldsOff), 16, 0, 0);
    }
    __syncthreads();

#pragma unroll
    for (int ks = 0; ks < 2; ++ks) {
      bf16x8 af[4], bfr[4];
      const int kcol = ks * 32 + (lane >> 4) * 8;
#pragma unroll
      for (int mi = 0; mi < 4; ++mi) {
        af[mi]  = *(const bf16x8*)&sA[(wr * 64 + mi * 16 + (lane & 15)) * BK + kcol];
        bfr[mi] = *(const bf16x8*)&sB[(wc * 64 + mi * 16 + (lane & 15)) * BK + kcol];
      }
#pragma unroll
      for (int mi = 0; mi < 4; ++mi)
#pragma unroll
        for (int ni = 0; ni < 4; ++ni)
          acc[mi][ni] = __builtin_amdgcn_mfma_f32_16x16x32_bf16(
              af[mi], bfr[ni], acc[mi][ni], 0, 0, 0);
    }
    __syncthreads();
  }

  // Epilogue: logits -> -log_sigmoid(label*logit) = softplus(-z), accumulate.
  const float scale = scale_p[0];
  const float bias  = bias_p[0];
  float loss = 0.0f;
  const int cBase = lane & 15;
  const int rBase = (lane >> 4) * 4;
#pragma unroll
  for (int mi = 0; mi < 4; ++mi) {
#pragma unroll
    for (int ni = 0; ni < 4; ++ni) {
      const int colL = sLabB[wc * 64 + ni * 16 + cBase];
#pragma unroll
      for (int r = 0; r < 4; ++r) {
        const int rowL = sLabA[wr * 64 + mi * 16 + rBase + r];
        const float logit = fmaf(scale, acc[mi][ni][r], bias);
        const float t = (rowL == colL) ? -logit : logit;  // t = -label*logit
        loss += fmaxf(t, 0.0f) + log1pf(__expf(-fabsf(t)));
      }
    }
  }

  // wave reduce (64 lanes), then cross-wave via LDS, one atomic per block.
#pragma unroll
  for (int off = 32; off > 0; off >>= 1) loss += __shfl_down(loss, off, 64);
  if (lane == 0) sPart[wid] = loss;
  __syncthreads();
  if (tid == 0) {
    const float s = (sPart[0] + sPart[1]) + (sPart[2] + sPart[3]);
    atomicAdd(out, s * (1.0f / (float)N_TOK));
  }
}

extern "C" void kernel_launch(void* const* d_in, const int* in_sizes, int n_in,
                              void* d_out, int out_size, void* d_ws, size_t ws_size,
                              hipStream_t stream) {
  const float* a  = (const float*)d_in[0];
  const float* b  = (const float*)d_in[1];
  const int*   la = (const int*)d_in[2];
  const int*   lb = (const int*)d_in[3];
  const float* sc = (const float*)d_in[4];
  const float* bi = (const float*)d_in[5];
  float* out = (float*)d_out;

  ushort* wa = (ushort*)d_ws;                       // bf16 A, 16 MB
  ushort* wb = wa + (size_t)N_TOK * D_K;            // bf16 B, 16 MB

  zero_out_kernel<<<1, 1, 0, stream>>>(out);
  convert_kernel<<<2048, 256, 0, stream>>>(a, b, wa, wb);
  dim3 grid(N_TOK / BN, N_TOK / BM);
  sigc_kernel<<<grid, 256, 0, stream>>>(wa, wb, la, lb, sc, bi, out);
}

// Round 2
// 208.461 us; speedup vs baseline: 1.7453x; 1.7453x over previous
//
#include <hip/hip_runtime.h>
#include <hip/hip_bf16.h>
#include <stdint.h>

#define N_TOK 8192
#define D_K   1024
#define BM    128
#define BN    128
#define BK    64

typedef __attribute__((ext_vector_type(8))) short bf16x8;
typedef __attribute__((ext_vector_type(4))) float f32x4;

__global__ void zero_out_kernel(float* out) { out[0] = 0.0f; }

__device__ __forceinline__ unsigned short f32_to_bf16_rne(float x) {
  uint32_t u = __builtin_bit_cast(uint32_t, x);
  uint32_t r = (u >> 16) & 1u;
  u += 0x7fffu + r;
  return (unsigned short)(u >> 16);
}

__global__ void __launch_bounds__(256)
convert_kernel(const float* __restrict__ a, const float* __restrict__ b,
               ushort* __restrict__ oa, ushort* __restrict__ ob) {
  const size_t total4 = (size_t)N_TOK * D_K / 4;
  size_t i = (size_t)blockIdx.x * blockDim.x + threadIdx.x;
  size_t stride = (size_t)gridDim.x * blockDim.x;
  for (; i < total4; i += stride) {
    float4 va = ((const float4*)a)[i];
    float4 vb = ((const float4*)b)[i];
    ushort4 ua, ub;
    ua.x = f32_to_bf16_rne(va.x); ua.y = f32_to_bf16_rne(va.y);
    ua.z = f32_to_bf16_rne(va.z); ua.w = f32_to_bf16_rne(va.w);
    ub.x = f32_to_bf16_rne(vb.x); ub.y = f32_to_bf16_rne(vb.y);
    ub.z = f32_to_bf16_rne(vb.z); ub.w = f32_to_bf16_rne(vb.w);
    ((ushort4*)oa)[i] = ua;
    ((ushort4*)ob)[i] = ub;
  }
}

// Fused GEMM + sigmoid-contrastive loss.
// LDS tiles are [128 rows][8 slots of 16B] with slot' = slot ^ (row&7)
// XOR-swizzle (T2). global_load_lds writes linearly, so the swizzle is
// applied by permuting the per-lane GLOBAL source column (rule #21); the
// LDS read applies the same XOR (involution).
__global__ void __launch_bounds__(256)
sigc_kernel(const ushort* __restrict__ A, const ushort* __restrict__ B,
            const int* __restrict__ labA, const int* __restrict__ labB,
            const float* __restrict__ scale_p, const float* __restrict__ bias_p,
            float* __restrict__ out) {
  __shared__ ushort sA[BM * BK];
  __shared__ ushort sB[BN * BK];
  __shared__ int sLabA[BM];
  __shared__ int sLabB[BN];
  __shared__ float sPart[4];

  const int tid  = threadIdx.x;
  const int lane = tid & 63;
  const int wid  = tid >> 6;
  const int wr   = wid >> 1;   // wave row (0/1)
  const int wc   = wid & 1;    // wave col (0/1)

  const int bRow = blockIdx.y * BM;
  const int bCol = blockIdx.x * BN;

  if (tid < BM) sLabA[tid] = labA[bRow + tid];
  else          sLabB[tid - BM] = labB[bCol + (tid - BM)];

  f32x4 acc[4][4];
#pragma unroll
  for (int i = 0; i < 4; ++i)
#pragma unroll
    for (int j = 0; j < 4; ++j) acc[i][j] = (f32x4){0.f, 0.f, 0.f, 0.f};

  // staging geometry: issue `it` of wave `wid` covers elements
  // e = (wid*4+it)*512 + lane*8 (linear LDS dest). Source column is
  // swizzled: srcSlot = slot ^ (row&7).
  const int eBase = wid * 2048 + lane * 8;

  for (int k0 = 0; k0 < D_K; k0 += BK) {
#pragma unroll
    for (int it = 0; it < 4; ++it) {
      const int e    = eBase + it * 512;
      const int row  = e >> 6;          // 0..127
      const int slot = (e >> 3) & 7;    // 16B slot within row
      const int srcCol = ((slot ^ (row & 7)) << 3);
      const int ldsOff = (wid * 4 + it) * 512;  // wave-uniform base (elements)
      const ushort* gA = A + (size_t)(bRow + row) * D_K + (k0 + srcCol);
      const ushort* gB = B + (size_t)(bCol + row) * D_K + (k0 + srcCol);
      __builtin_amdgcn_global_load_lds(
          (const __attribute__((address_space(1))) void*)gA,
          (__attribute__((address_space(3))) void*)(sA + ldsOff), 16, 0, 0);
      __builtin_amdgcn_global_load_lds(
          (const __attribute__((address_space(1))) void*)gB,
          (__attribute__((address_space(3))) void*)(sB + ldsOff), 16, 0, 0);
    }
    __syncthreads();

    const int rA = wr * 64 + (lane & 15);
    const int rB = wc * 64 + (lane & 15);
    const int sHi = lane >> 4;          // 0..3
#pragma unroll
    for (int ks = 0; ks < 2; ++ks) {
      bf16x8 af[4], bfr[4];
      const int s = ks * 4 + sHi;       // 16B slot index (0..7)
#pragma unroll
      for (int mi = 0; mi < 4; ++mi) {
        const int ra = rA + mi * 16;
        const int rb = rB + mi * 16;
        af[mi]  = *(const bf16x8*)&sA[ra * BK + ((s ^ (ra & 7)) << 3)];
        bfr[mi] = *(const bf16x8*)&sB[rb * BK + ((s ^ (rb & 7)) << 3)];
      }
#pragma unroll
      for (int mi = 0; mi < 4; ++mi)
#pragma unroll
        for (int ni = 0; ni < 4; ++ni)
          acc[mi][ni] = __builtin_amdgcn_mfma_f32_16x16x32_bf16(
              af[mi], bfr[ni], acc[mi][ni], 0, 0, 0);
    }
    __syncthreads();
  }

  // Epilogue: -log_sigmoid(label*logit) = softplus(-label*logit)
  //         = max(t,0) + log(1+exp(-|t|)),  t = -label*logit.
  const float scale = scale_p[0];
  const float bias  = bias_p[0];
  float loss = 0.0f;
  const int cBase = lane & 15;
  const int rBase = (lane >> 4) * 4;
#pragma unroll
  for (int mi = 0; mi < 4; ++mi) {
#pragma unroll
    for (int ni = 0; ni < 4; ++ni) {
      const int colL = sLabB[wc * 64 + ni * 16 + cBase];
#pragma unroll
      for (int r = 0; r < 4; ++r) {
        const int rowL = sLabA[wr * 64 + mi * 16 + rBase + r];
        const float logit = fmaf(scale, acc[mi][ni][r], bias);
        const float t = (rowL == colL) ? -logit : logit;  // t = -label*logit
        loss += fmaxf(t, 0.0f) + __logf(1.0f + __expf(-fabsf(t)));
      }
    }
  }

  // wave reduce (64 lanes), then cross-wave via LDS, one atomic per block.
#pragma unroll
  for (int off = 32; off > 0; off >>= 1) loss += __shfl_down(loss, off, 64);
  if (lane == 0) sPart[wid] = loss;
  __syncthreads();
  if (tid == 0) {
    const float s = (sPart[0] + sPart[1]) + (sPart[2] + sPart[3]);
    atomicAdd(out, s * (1.0f / (float)N_TOK));
  }
}

extern "C" void kernel_launch(void* const* d_in, const int* in_sizes, int n_in,
                              void* d_out, int out_size, void* d_ws, size_t ws_size,
                              hipStream_t stream) {
  const float* a  = (const float*)d_in[0];
  const float* b  = (const float*)d_in[1];
  const int*   la = (const int*)d_in[2];
  const int*   lb = (const int*)d_in[3];
  const float* sc = (const float*)d_in[4];
  const float* bi = (const float*)d_in[5];
  float* out = (float*)d_out;

  ushort* wa = (ushort*)d_ws;                       // bf16 A, 16 MB
  ushort* wb = wa + (size_t)N_TOK * D_K;            // bf16 B, 16 MB

  zero_out_kernel<<<1, 1, 0, stream>>>(out);
  convert_kernel<<<2048, 256, 0, stream>>>(a, b, wa, wb);
  dim3 grid(N_TOK / BN, N_TOK / BM);
  sigc_kernel<<<grid, 256, 0, stream>>>(wa, wb, la, lb, sc, bi, out);
}

// Round 3
// 182.403 us; speedup vs baseline: 1.9946x; 1.1429x over previous
//
#include <hip/hip_runtime.h>
#include <hip/hip_bf16.h>
#include <stdint.h>

#define N_TOK 8192
#define D_K   1024
#define BM    256
#define BN    256
#define BK    64
#define NT    (D_K / BK)          // 16 K-tiles
#define TILE_ELEMS (BM * BK)      // 16384 elements per operand buffer

typedef __attribute__((ext_vector_type(8))) short bf16x8;
typedef __attribute__((ext_vector_type(4))) float f32x4;

__global__ void zero_out_kernel(float* out) { out[0] = 0.0f; }

__device__ __forceinline__ unsigned short f32_to_bf16_rne(float x) {
  uint32_t u = __builtin_bit_cast(uint32_t, x);
  uint32_t r = (u >> 16) & 1u;
  u += 0x7fffu + r;
  return (unsigned short)(u >> 16);
}

__global__ void __launch_bounds__(256)
convert_kernel(const float* __restrict__ a, const float* __restrict__ b,
               ushort* __restrict__ oa, ushort* __restrict__ ob) {
  const size_t total4 = (size_t)N_TOK * D_K / 4;
  size_t i = (size_t)blockIdx.x * blockDim.x + threadIdx.x;
  size_t stride = (size_t)gridDim.x * blockDim.x;
  for (; i < total4; i += stride) {
    float4 va = ((const float4*)a)[i];
    float4 vb = ((const float4*)b)[i];
    ushort4 ua, ub;
    ua.x = f32_to_bf16_rne(va.x); ua.y = f32_to_bf16_rne(va.y);
    ua.z = f32_to_bf16_rne(va.z); ua.w = f32_to_bf16_rne(va.w);
    ub.x = f32_to_bf16_rne(vb.x); ub.y = f32_to_bf16_rne(vb.y);
    ub.z = f32_to_bf16_rne(vb.z); ub.w = f32_to_bf16_rne(vb.w);
    ((ushort4*)oa)[i] = ua;
    ((ushort4*)ob)[i] = ub;
  }
}

// Stage one operand's K-tile (256 rows x 64 cols bf16) into LDS.
// Linear LDS dest (wave-uniform base + lane*16B); swizzle applied on the
// GLOBAL source column: srcSlot = slot ^ (row&7)  (rule #21 / T2).
// 4 wave-instructions per thread => 4 vmcnt slots per call.
__device__ __forceinline__ void stage_tile(const ushort* __restrict__ G,
                                           int baseRow, int k0, ushort* lds,
                                           int tid, int wid) {
#pragma unroll
  for (int i = 0; i < 4; ++i) {
    const int e    = i * 4096 + tid * 8;
    const int row  = e >> 6;            // 0..255
    const int slot = (e >> 3) & 7;
    const int srcCol = (slot ^ (row & 7)) << 3;
    const ushort* g = G + (size_t)(baseRow + row) * D_K + (k0 + srcCol);
    __builtin_amdgcn_global_load_lds(
        (const __attribute__((address_space(1))) void*)g,
        (__attribute__((address_space(3))) void*)(lds + i * 4096 + wid * 512),
        16, 0, 0);
  }
}

// Fused 256x256-tile bf16 MFMA GEMM + sigmoid-contrastive loss.
// 8 waves (2 row x 4 col), per-wave output 128x64 (acc[2][4][4] f32x4).
// Double-buffered LDS, counted vmcnt(8) (never 0 in main loop), raw
// s_barrier, setprio around MFMA clusters (T3+T4+T5), XCD swizzle (T1).
__global__ void __launch_bounds__(512)
sigc_kernel(const ushort* __restrict__ A, const ushort* __restrict__ B,
            const int* __restrict__ labA, const int* __restrict__ labB,
            const float* __restrict__ scale_p, const float* __restrict__ bias_p,
            float* __restrict__ out) {
  __shared__ ushort sA[2 * TILE_ELEMS];   // 64 KB
  __shared__ ushort sB[2 * TILE_ELEMS];   // 64 KB
  __shared__ int sLabA[BM];
  __shared__ int sLabB[BN];
  __shared__ float sPart[8];

  const int tid  = threadIdx.x;
  const int lane = tid & 63;
  const int wid  = tid >> 6;      // 0..7
  const int wr   = wid >> 2;      // 0..1 (row half)
  const int wc   = wid & 3;       // 0..3 (col quarter)

  // XCD-aware block swizzle: grid = 1024 (divisible by 8).
  const int bid  = (int)blockIdx.x;
  const int swz  = (bid & 7) * 128 + (bid >> 3);
  const int bRow = (swz >> 5) * BM;       // 32 tiles per dim
  const int bCol = (swz & 31) * BN;

  if (tid < 256) sLabA[tid] = labA[bRow + tid];
  else           sLabB[tid - 256] = labB[bCol + (tid - 256)];

  f32x4 acc[2][4][4];
#pragma unroll
  for (int q = 0; q < 2; ++q)
#pragma unroll
    for (int i = 0; i < 4; ++i)
#pragma unroll
      for (int j = 0; j < 4; ++j) acc[q][i][j] = (f32x4){0.f, 0.f, 0.f, 0.f};

  // Prologue: stage tiles 0,1; full drain once (also publishes labels).
  stage_tile(A, bRow, 0, sA, tid, wid);
  stage_tile(B, bCol, 0, sB, tid, wid);
  stage_tile(A, bRow, BK, sA + TILE_ELEMS, tid, wid);
  stage_tile(B, bCol, BK, sB + TILE_ELEMS, tid, wid);
  __syncthreads();

  const int lr  = lane & 15;
  const int sHi = lane >> 4;      // 0..3

  for (int t = 0; t < NT; ++t) {
    const int cur = t & 1;
    const ushort* sAc = sA + cur * TILE_ELEMS;
    const ushort* sBc = sB + cur * TILE_ELEMS;

    // B fragments: hoisted once per K-tile (8 ds_read_b128).
    bf16x8 bf[4][2];
#pragma unroll
    for (int ni = 0; ni < 4; ++ni) {
      const int row = wc * 64 + ni * 16 + lr;
#pragma unroll
      for (int ks = 0; ks < 2; ++ks) {
        const int s = ks * 4 + sHi;
        bf[ni][ks] = *(const bf16x8*)&sBc[row * BK + ((s ^ (row & 7)) << 3)];
      }
    }
#pragma unroll
    for (int qr = 0; qr < 2; ++qr) {
      bf16x8 af[4][2];
#pragma unroll
      for (int mi = 0; mi < 4; ++mi) {
        const int row = wr * 128 + qr * 64 + mi * 16 + lr;
#pragma unroll
        for (int ks = 0; ks < 2; ++ks) {
          const int s = ks * 4 + sHi;
          af[mi][ks] = *(const bf16x8*)&sAc[row * BK + ((s ^ (row & 7)) << 3)];
        }
      }
      __builtin_amdgcn_s_setprio(1);
#pragma unroll
      for (int ks = 0; ks < 2; ++ks)
#pragma unroll
        for (int mi = 0; mi < 4; ++mi)
#pragma unroll
          for (int ni = 0; ni < 4; ++ni)
            acc[qr][mi][ni] = __builtin_amdgcn_mfma_f32_16x16x32_bf16(
                af[mi][ks], bf[ni][ks], acc[qr][mi][ni], 0, 0, 0);
      __builtin_amdgcn_s_setprio(0);
    }

    if (t < NT - 1) {
      // (1) all waves done reading buf[cur] -> safe to overwrite.
      __builtin_amdgcn_sched_barrier(0);
      __builtin_amdgcn_s_barrier();
      if (t < NT - 2) {
        ushort* dA = sA + cur * TILE_ELEMS;
        ushort* dB = sB + cur * TILE_ELEMS;
        stage_tile(A, bRow, (t + 2) * BK, dA, tid, wid);
        stage_tile(B, bCol, (t + 2) * BK, dB, tid, wid);
        // Counted wait: 8 newest = tile t+2; everything older (tile t+1)
        // has landed. Never drain to 0 in the main loop (T4).
        asm volatile("s_waitcnt vmcnt(8)" ::: "memory");
      } else {
        asm volatile("s_waitcnt vmcnt(0)" ::: "memory");
      }
      // (2) all waves' tile t+1 loads landed -> safe to read next buffer.
      __builtin_amdgcn_sched_barrier(0);
      __builtin_amdgcn_s_barrier();
    }
  }

  // Epilogue: -log_sigmoid(label*logit) = max(t,0) + log(1+exp(-|t|)).
  const float scale = scale_p[0];
  const float bias  = bias_p[0];
  float loss = 0.0f;
  const int cBase = lane & 15;
  const int rBase = (lane >> 4) * 4;
#pragma unroll
  for (int qr = 0; qr < 2; ++qr) {
#pragma unroll
    for (int mi = 0; mi < 4; ++mi) {
#pragma unroll
      for (int ni = 0; ni < 4; ++ni) {
        const int colL = sLabB[wc * 64 + ni * 16 + cBase];
#pragma unroll
        for (int r = 0; r < 4; ++r) {
          const int rowL = sLabA[wr * 128 + qr * 64 + mi * 16 + rBase + r];
          const float logit = fmaf(scale, acc[qr][mi][ni][r], bias);
          const float tt = (rowL == colL) ? -logit : logit;
          loss += fmaxf(tt, 0.0f) + __logf(1.0f + __expf(-fabsf(tt)));
        }
      }
    }
  }

#pragma unroll
  for (int off = 32; off > 0; off >>= 1) loss += __shfl_down(loss, off, 64);
  if (lane == 0) sPart[wid] = loss;
  __syncthreads();
  if (tid == 0) {
    float s = 0.f;
#pragma unroll
    for (int w = 0; w < 8; ++w) s += sPart[w];
    atomicAdd(out, s * (1.0f / (float)N_TOK));
  }
}

extern "C" void kernel_launch(void* const* d_in, const int* in_sizes, int n_in,
                              void* d_out, int out_size, void* d_ws, size_t ws_size,
                              hipStream_t stream) {
  const float* a  = (const float*)d_in[0];
  const float* b  = (const float*)d_in[1];
  const int*   la = (const int*)d_in[2];
  const int*   lb = (const int*)d_in[3];
  const float* sc = (const float*)d_in[4];
  const float* bi = (const float*)d_in[5];
  float* out = (float*)d_out;

  ushort* wa = (ushort*)d_ws;                       // bf16 A, 16 MB
  ushort* wb = wa + (size_t)N_TOK * D_K;            // bf16 B, 16 MB

  zero_out_kernel<<<1, 1, 0, stream>>>(out);
  convert_kernel<<<2048, 256, 0, stream>>>(a, b, wa, wb);
  const int grid = (N_TOK / BM) * (N_TOK / BN);     // 1024
  sigc_kernel<<<grid, 512, 0, stream>>>(wa, wb, la, lb, sc, bi, out);
}